// Round 20
// baseline (88.509 us; speedup 1.0000x reference)
//
#include <hip/hip_runtime.h>
#include <hip/hip_fp16.h>
#include <math.h>

#define HH 512
#define WW 512
#define BB 4
#define NCLS 20
#define NINST 32
#define NPIX (HH*WW)
#define NCH 24
#define NBIN 128                // bins over err/2 in [0,1]
#define NCHUNK3 128
#define CPX3 2048
#define K3T 512
#define HSTR 33                 // bank(bin*33+j)%32=(bin+j)%32 -> conflict-free

// ---- workspace layout (bytes) ----
#define OFF_PARTA  ((size_t)0)                       // float[2048][256] = 2MB
#define OFF_PSEED  (OFF_PARTA + 2048*256*4)          // float2[2048]
#define OFF_STATS  (OFF_PSEED + 2048*8)              // float[8][128]
#define OFF_SEEDBG (OFF_STATS + 8*128*4)             // float[4]
#define OFF_VALID  (OFF_SEEDBG + 4*4)                // float[4]
#define OFF_SFG    (OFF_VALID + 4*4)                 // float[512]
#define OFF_REC    ((OFF_SFG + 512*4 + 255) & ~(size_t)255)  // uint2[B][NPIX] = 8MB
#define OFF_HIST   (OFF_REC + (size_t)BB*NPIX*8)     // u32[B][128][32][128] = 8MB

__device__ __forceinline__ float fast_rcp(float x) { return __builtin_amdgcn_rcpf(x); }
__device__ __forceinline__ float fast_sigmoid(float z) { return fast_rcp(1.0f + __expf(-z)); }
__device__ __forceinline__ float fast_tanh(float x) {
  return 1.0f - 2.0f * fast_rcp(__expf(2.0f * x) + 1.0f);
}

// K1: 2048 blocks, 2 px/thread. Seed loop = 4 groups x 5 batched float2
// loads (ILP=5) while staying <64 VGPR (TLP=8 waves/SIMD): both at once.
__global__ __launch_bounds__(256) void k1_stats(
    const float* __restrict__ pred, const int* __restrict__ inst,
    const int* __restrict__ lab,
    float* __restrict__ partA, float2* __restrict__ partSeed,
    uint2* __restrict__ rec, float* __restrict__ outz)
{
  __shared__ unsigned s_st[4][NINST][9];  // [0]=cnt|G<<16, [1..6]=float bits
  __shared__ float s_seed, s_valid;
  int t = threadIdx.x;
  int w = t >> 6;
  for (int i = t; i < 4*NINST*9; i += 256) ((unsigned*)s_st)[i] = 0u;
  if (t == 0) { s_seed = 0.f; s_valid = 0.f; }
  if (blockIdx.x == 0 && t == 0) outz[0] = 0.f;   // zero out before k4_final
  __syncthreads();

  int b = blockIdx.x >> 9;                // 512 blocks per image
  int p = (blockIdx.x & 511) * 512 + t * 2;
  const float* pb = pred + (size_t)b*NCH*NPIX;
  float2 e0v = *(const float2*)(pb + p);
  float2 e1v = *(const float2*)(pb + NPIX + p);
  float2 g0v = *(const float2*)(pb + 2*NPIX + p);
  float2 g1v = *(const float2*)(pb + 3*NPIX + p);
  int2 idv = *(const int2*)(inst + (size_t)b*NPIX + p);
  int2 lbv = *(const int2*)(lab + (size_t)b*NPIX + p);

  #pragma unroll
  for (int u = 0; u < 2; ++u) {
    int px = p + u;
    int x = px & (WW-1);
    int y = px >> 9;
    float xm = x * (1.0f/(WW-1));
    float ym = y * (1.0f/(HH-1));
    float g0 = (&g0v.x)[u];
    float g1 = (&g1v.x)[u];
    int id = (&idv.x)[u];
    int lb = (&lbv.x)[u];
    if (id >= 1) {
      int j = id - 1;
      unsigned* row = s_st[w][j];
      atomicAdd(&row[0], 1u | ((lb != 255) ? 0x10000u : 0u));
      atomicAdd((float*)&row[1], xm);
      atomicAdd((float*)&row[2], ym);
      atomicAdd((float*)&row[3], g0);
      atomicAdd((float*)&row[4], g1);
      atomicAdd((float*)&row[5], g0*g0);
      atomicAdd((float*)&row[6], g1*g1);
    }
  }

  // seed loop: ILP-5 batched loads, 4 groups (all indices static).
  float so0 = 0.f, so1 = 0.f, Sv0 = 0.f, Sv1 = 0.f;
  #pragma unroll
  for (int g = 0; g < 4; ++g) {
    float2 svb[5];
    #pragma unroll
    for (int k = 0; k < 5; ++k)
      svb[k] = *(const float2*)(pb + (size_t)(4 + g*5 + k)*NPIX + p);
    #pragma unroll
    for (int k = 0; k < 5; ++k) {
      int c = g*5 + k;
      float sg0 = fast_sigmoid(svb[k].x);
      float sg1 = fast_sigmoid(svb[k].y);
      Sv0 += sg0*sg0;
      Sv1 += sg1*sg1;
      if (c + 1 == lbv.x) so0 = sg0;
      if (c + 1 == lbv.y) so1 = sg1;
    }
  }
  float seedloc = 0.f, vloc = 0.f;
  if (lbv.x != 255) { seedloc += Sv0 - so0*so0; vloc += 1.0f; }
  if (lbv.y != 255) { seedloc += Sv1 - so1*so1; vloc += 1.0f; }

  // rec: {f16 ex, f16 ey, u8 sg_own, u8 (id | valid<<7)}
  {
    uint2 r4[2];
    #pragma unroll
    for (int u = 0; u < 2; ++u) {
      int px = p + u;
      int x = px & (WW-1);
      int y = px >> 9;
      float ex = fast_tanh((&e0v.x)[u]) + x * (1.0f/(WW-1));
      float ey = fast_tanh((&e1v.x)[u]) + y * (1.0f/(HH-1));
      __half2 h = __floats2half2_rn(ex, ey);
      unsigned valid = (((&lbv.x)[u]) != 255) ? 1u : 0u;
      unsigned meta = (unsigned)(&idv.x)[u] | (valid << 7);
      float sou = u ? so1 : so0;
      r4[u].x = *reinterpret_cast<unsigned*>(&h);
      r4[u].y = (unsigned)(unsigned char)(sou*255.f + 0.5f) | (meta << 8);
    }
    *(uint4*)(rec + (size_t)b*NPIX + p) = make_uint4(r4[0].x, r4[0].y, r4[1].x, r4[1].y);
  }
  for (int o = 32; o; o >>= 1) {
    seedloc += __shfl_down(seedloc, o);
    vloc    += __shfl_down(vloc, o);
  }
  if ((t & 63) == 0) { atomicAdd(&s_seed, seedloc); atomicAdd(&s_valid, vloc); }
  __syncthreads();

  {
    int j = t & 31, f = t >> 5;
    float v;
    if (f == 0) {
      unsigned s = (s_st[0][j][0] & 0xFFFFu) + (s_st[1][j][0] & 0xFFFFu)
                 + (s_st[2][j][0] & 0xFFFFu) + (s_st[3][j][0] & 0xFFFFu);
      v = (float)s;
    } else if (f == 7) {
      unsigned s = (s_st[0][j][0] >> 16) + (s_st[1][j][0] >> 16)
                 + (s_st[2][j][0] >> 16) + (s_st[3][j][0] >> 16);
      v = (float)s;
    } else {
      v = __uint_as_float(s_st[0][j][f]) + __uint_as_float(s_st[1][j][f])
        + __uint_as_float(s_st[2][j][f]) + __uint_as_float(s_st[3][j][f]);
    }
    partA[(blockIdx.x << 8) + t] = v;
  }
  if (t == 0) partSeed[blockIdx.x] = make_float2(s_seed, s_valid);
}

// K2a: 33 blocks. 0-31: (image,field) reduction over 512 partials -> stats.
// 32: seed/valid reduction.
__global__ __launch_bounds__(256) void k2a_reduce(
    const float* __restrict__ partA, const float2* __restrict__ partSeed,
    float* __restrict__ stats, float* __restrict__ seedbg,
    float* __restrict__ validT)
{
  int bid = blockIdx.x;
  int t = threadIdx.x;
  if (bid < 32) {
    __shared__ float red[256];
    int b = bid >> 3, f = bid & 7;
    int j = t & 31, grp = t >> 5;           // 8 groups x 64 blocks
    float s = 0.f;
    #pragma unroll 8
    for (int k = 0; k < 64; ++k)
      s += partA[((b*512 + grp*64 + k) << 8) + (f << 5) + j];
    red[t] = s; __syncthreads();
    for (int st = 128; st >= 32; st >>= 1) {
      if (t < st) red[t] += red[t + st];
      __syncthreads();
    }
    if (t < 32) stats[f*128 + b*32 + t] = red[t];
  } else {
    int img = t >> 6, slot = t & 63;
    float s = 0.f, v = 0.f;
    #pragma unroll
    for (int k = 0; k < 8; ++k) {
      float2 ps = partSeed[img*512 + slot*8 + k];
      s += ps.x; v += ps.y;
    }
    for (int o = 32; o; o >>= 1) {
      s += __shfl_down(s, o);
      v += __shfl_down(v, o);
    }
    if (slot == 0) { seedbg[img] = s; validT[img] = v; }
  }
}

// K3: block=(image, 2048-px chunk); lane=(slot<<5)|instance; uint4 loads
// (2 px/lane/round); conflict-free LDS atomics; bin-0 skipped.
__global__ __launch_bounds__(K3T) void k3_hist(
    const uint2* __restrict__ rec, const float* __restrict__ stats,
    unsigned* __restrict__ hist, float* __restrict__ sfg)
{
  __shared__ unsigned hc[NBIN*HSTR];      // 16.9 KB
  __shared__ float sder[NINST][4];
  __shared__ float s_fg[8];
  int t = threadIdx.x;
  int bid = blockIdx.x;                   // 512
  int b = bid >> 7;
  int chunk = bid & 127;
  for (int i = t; i < NBIN*HSTR; i += K3T) hc[i] = 0u;
  if (t < NINST) {
    int pr = b*NINST + t;
    float cnt = fmaxf(stats[0*128+pr], 1.0f);
    float rc = fast_rcp(cnt);
    sder[t][0] = stats[1*128+pr] * rc;
    sder[t][1] = stats[2*128+pr] * rc;
    sder[t][2] = -1.442695041f * __expf(10.f * stats[3*128+pr] * rc);
    sder[t][3] = -1.442695041f * __expf(10.f * stats[4*128+pr] * rc);
  }
  __syncthreads();

  int w = t >> 6, lane = t & 63;
  int j = lane & 31, jp1 = j + 1;
  float cx = sder[j][0], cy = sder[j][1];
  float s0 = sder[j][2], s1 = sder[j][3];
  const uint4* base4 = (const uint4*)(rec + (size_t)b*NPIX + chunk*CPX3)
                       + w*128 + (lane >> 5);
  unsigned* hrow = hc + j;
  float fg = 0.f;

  #pragma unroll 4
  for (int r = 0; r < 64; ++r) {
    uint4 rv = base4[r*2];
    #pragma unroll
    for (int u = 0; u < 2; ++u) {
      unsigned lo = u ? rv.z : rv.x;
      unsigned hi = u ? rv.w : rv.y;
      __half2 h;
      *reinterpret_cast<unsigned*>(&h) = lo;
      float2 e = __half22float2(h);
      float dx = e.x - cx, dy = e.y - cy;
      float dist = exp2f(dx*dx*s0 + dy*dy*s1);
      bool own = ((int)((hi >> 8) & 0x3F) == jp1);
      if (own) { float d = (float)(hi & 0xFFu)*(1.0f/255.f) - dist; fg += d*d; }
      if (hi & 0x8000u) {
        float f = own ? (1.0f - dist) : dist;
        unsigned bin = min((unsigned)(f * (float)NBIN), NBIN-1u);
        if (bin) atomicAdd(&hrow[bin*HSTR], own ? 0x10001u : 1u);
      }
    }
  }
  for (int o = 32; o; o >>= 1) fg += __shfl_down(fg, o);
  if (lane == 0) s_fg[w] = fg;
  __syncthreads();
  if (t == 0) {
    float s = 0.f;
    #pragma unroll
    for (int i = 0; i < 8; ++i) s += s_fg[i];
    sfg[bid] = 10.0f * s;
  }
  unsigned* out = hist + (size_t)(b*NCHUNK3 + chunk) * (NINST*NBIN);
  #pragma unroll
  for (int k = 0; k < NINST*NBIN/K3T; ++k) {
    int idx = k*K3T + t;
    out[idx] = hc[(idx & 127)*HSTR + (idx >> 7)];
  }
}

// K4: per pair: reduce 128 chunk hists, reconstruct bin-0 exactly, Lovasz
// scan, accumulate into out[0] (zeroed by k1). Block 0 adds seed terms.
__global__ __launch_bounds__(512) void k4_final(
    const unsigned* __restrict__ hist, const float* __restrict__ stats,
    const float* __restrict__ validT, const float* __restrict__ seedbg,
    const float* __restrict__ sfg, float* __restrict__ out)
{
  __shared__ unsigned s_c[4][NBIN], s_p[4][NBIN];
  __shared__ unsigned rc[NBIN], rp[NBIN];
  __shared__ float s_L;
  int t = threadIdx.x;
  int pair = blockIdx.x;
  int b = pair >> 5, j = pair & 31;
  int grp = t >> 7, bin = t & 127;
  const unsigned* bp = hist + ((size_t)b*NCHUNK3*NINST + j)*NBIN + bin;
  unsigned c = 0, p = 0;
  #pragma unroll 8
  for (int ch = grp*32; ch < grp*32 + 32; ++ch) {
    unsigned v = bp[(size_t)ch * (NINST*NBIN)];
    c += v & 0xFFFFu; p += v >> 16;
  }
  s_c[grp][bin] = c; s_p[grp][bin] = p;
  __syncthreads();
  if (t < NBIN) {
    unsigned cc = s_c[0][t] + s_c[1][t] + s_c[2][t] + s_c[3][t];
    unsigned pp = s_p[0][t] + s_p[1][t] + s_p[2][t] + s_p[3][t];
    s_c[0][t] = cc; s_p[0][t] = pp;
    rc[t] = t ? cc : 0u; rp[t] = t ? pp : 0u;
  }
  __syncthreads();
  for (int st = 64; st; st >>= 1) {
    if (t < st) { rc[t] += rc[t+st]; rp[t] += rp[t+st]; }
    __syncthreads();
  }
  float G = stats[7*128+pair];
  if (t == 0) {
    s_c[0][0] = (unsigned)validT[b] - rc[0];
    s_p[0][0] = (unsigned)G - rp[0];
  }
  __syncthreads();

  if (t < 64) {
    int lane = t;
    unsigned carryN = 0, carryP = 0;
    float Jprev = 0.f, L = 0.f;
    for (int c8 = 0; c8 < NBIN/64; ++c8) {
      int k = NBIN - 1 - c8*64 - lane;
      unsigned n = s_c[0][k], pp0 = s_p[0][k];
      for (int off = 1; off < 64; off <<= 1) {
        unsigned nn = __shfl_up(n, off);
        unsigned pq = __shfl_up(pp0, off);
        if (lane >= off) { n += nn; pp0 += pq; }
      }
      float fN = (float)(carryN + n);
      float fP = (float)(carryP + pp0);
      float uni = G + fN - fP;
      float J = 1.0f - (G - fP) / fmaxf(uni, 1e-9f);
      float Jp = __shfl_up(J, 1);
      if (lane == 0) Jp = Jprev;
      float v = (k + 0.5f) * (2.0f/NBIN);
      L += v * (J - Jp);
      carryN += __shfl(n, 63);
      carryP += __shfl(pp0, 63);
      Jprev  = __shfl(J, 63);
    }
    for (int o = 32; o; o >>= 1) L += __shfl_down(L, o);
    if (lane == 0) s_L = L;
  }
  __syncthreads();
  if (t == 0) {
    float cntA = stats[0*128+pair];
    float cnt = fmaxf(cntA, 1.0f);
    float s0 = stats[3*128+pair], s1 = stats[4*128+pair];
    float q0 = stats[5*128+pair], q1 = stats[6*128+pair];
    float sm0 = s0/cnt, sm1 = s1/cnt;
    float varnum = q0 - 2.f*sm0*s0 + cntA*sm0*sm0
                 + q1 - 2.f*sm1*s1 + cntA*sm1*sm1;
    float varl = varnum / (2.0f * cnt);
    atomicAdd(out, (s_L + 10.0f*varl) * (1.0f/(NINST*BB)));
  }
  if (pair == 0) {
    __shared__ float red[512];
    float acc = sfg[t];
    if (t < 4) acc += seedbg[t];
    red[t] = acc; __syncthreads();
    for (int st = 256; st; st >>= 1) {
      if (t < st) red[t] += red[t+st];
      __syncthreads();
    }
    if (t == 0) atomicAdd(out, red[0] * (1.0f/((float)NPIX*BB)));
  }
}

extern "C" void kernel_launch(void* const* d_in, const int* in_sizes, int n_in,
                              void* d_out, int out_size, void* d_ws, size_t ws_size,
                              hipStream_t stream)
{
  const float* pred = (const float*)d_in[0];
  const int* inst = (const int*)d_in[1];
  const int* lab  = (const int*)d_in[2];
  char* ws = (char*)d_ws;
  float* partA = (float*)(ws + OFF_PARTA);
  float2* partSeed = (float2*)(ws + OFF_PSEED);
  float* stats = (float*)(ws + OFF_STATS);
  float* seedbg = (float*)(ws + OFF_SEEDBG);
  float* validT = (float*)(ws + OFF_VALID);
  float* sfg = (float*)(ws + OFF_SFG);
  uint2* rec = (uint2*)(ws + OFF_REC);
  unsigned* hist = (unsigned*)(ws + OFF_HIST);

  hipLaunchKernelGGL(k1_stats, dim3(2048), dim3(256), 0, stream,
                     pred, inst, lab, partA, partSeed, rec, (float*)d_out);
  hipLaunchKernelGGL(k2a_reduce, dim3(33), dim3(256), 0, stream,
                     partA, partSeed, stats, seedbg, validT);
  hipLaunchKernelGGL(k3_hist, dim3(BB*NCHUNK3), dim3(K3T), 0, stream,
                     rec, stats, hist, sfg);
  hipLaunchKernelGGL(k4_final, dim3(128), dim3(512), 0, stream,
                     hist, stats, validT, seedbg, sfg, (float*)d_out);
}

// Round 21
// 87.022 us; speedup vs baseline: 1.0171x; 1.0171x over previous
//
#include <hip/hip_runtime.h>
#include <hip/hip_fp16.h>
#include <math.h>

#define HH 512
#define WW 512
#define BB 4
#define NCLS 20
#define NINST 32
#define NPIX (HH*WW)
#define NCH 24
#define NBIN 64                 // bins over err/2 in [0,1]
#define NCHUNK3 128
#define CPX3 2048
#define K3T 512
#define HSTR 33                 // bank(bin*33+j)%32=(bin+j)%32 -> conflict-free

// ---- workspace layout (bytes) ----
#define OFF_PARTA  ((size_t)0)                       // float[2048][256] = 2MB
#define OFF_PSEED  (OFF_PARTA + 2048*256*4)          // float2[2048]
#define OFF_STATS  (OFF_PSEED + 2048*8)              // float[8][128]
#define OFF_SEEDBG (OFF_STATS + 8*128*4)             // float[4]
#define OFF_VALID  (OFF_SEEDBG + 4*4)                // float[4]
#define OFF_SFG    (OFF_VALID + 4*4)                 // float[512]
#define OFF_REC    ((OFF_SFG + 512*4 + 255) & ~(size_t)255)  // uint2[B][NPIX] = 8MB
#define OFF_HIST   (OFF_REC + (size_t)BB*NPIX*8)     // u32[B][128][32][64] = 4MB

__device__ __forceinline__ float fast_rcp(float x) { return __builtin_amdgcn_rcpf(x); }
__device__ __forceinline__ float fast_sigmoid(float z) { return fast_rcp(1.0f + __expf(-z)); }
__device__ __forceinline__ float fast_tanh(float x) {
  return 1.0f - 2.0f * fast_rcp(__expf(2.0f * x) + 1.0f);
}

// K1: 2048 blocks, 2 px/thread (unchanged from R20-passing version).
__global__ __launch_bounds__(256) void k1_stats(
    const float* __restrict__ pred, const int* __restrict__ inst,
    const int* __restrict__ lab,
    float* __restrict__ partA, float2* __restrict__ partSeed,
    uint2* __restrict__ rec, float* __restrict__ outz)
{
  __shared__ unsigned s_st[4][NINST][9];  // [0]=cnt|G<<16, [1..6]=float bits
  __shared__ float s_seed, s_valid;
  int t = threadIdx.x;
  int w = t >> 6;
  for (int i = t; i < 4*NINST*9; i += 256) ((unsigned*)s_st)[i] = 0u;
  if (t == 0) { s_seed = 0.f; s_valid = 0.f; }
  if (blockIdx.x == 0 && t == 0) outz[0] = 0.f;   // zero out before k4_final
  __syncthreads();

  int b = blockIdx.x >> 9;                // 512 blocks per image
  int p = (blockIdx.x & 511) * 512 + t * 2;
  const float* pb = pred + (size_t)b*NCH*NPIX;
  float2 e0v = *(const float2*)(pb + p);
  float2 e1v = *(const float2*)(pb + NPIX + p);
  float2 g0v = *(const float2*)(pb + 2*NPIX + p);
  float2 g1v = *(const float2*)(pb + 3*NPIX + p);
  int2 idv = *(const int2*)(inst + (size_t)b*NPIX + p);
  int2 lbv = *(const int2*)(lab + (size_t)b*NPIX + p);

  #pragma unroll
  for (int u = 0; u < 2; ++u) {
    int px = p + u;
    int x = px & (WW-1);
    int y = px >> 9;
    float xm = x * (1.0f/(WW-1));
    float ym = y * (1.0f/(HH-1));
    float g0 = (&g0v.x)[u];
    float g1 = (&g1v.x)[u];
    int id = (&idv.x)[u];
    int lb = (&lbv.x)[u];
    if (id >= 1) {
      int j = id - 1;
      unsigned* row = s_st[w][j];
      atomicAdd(&row[0], 1u | ((lb != 255) ? 0x10000u : 0u));
      atomicAdd((float*)&row[1], xm);
      atomicAdd((float*)&row[2], ym);
      atomicAdd((float*)&row[3], g0);
      atomicAdd((float*)&row[4], g1);
      atomicAdd((float*)&row[5], g0*g0);
      atomicAdd((float*)&row[6], g1*g1);
    }
  }

  float so0 = 0.f, so1 = 0.f, Sv0 = 0.f, Sv1 = 0.f;
  #pragma unroll
  for (int g = 0; g < 4; ++g) {
    float2 svb[5];
    #pragma unroll
    for (int k = 0; k < 5; ++k)
      svb[k] = *(const float2*)(pb + (size_t)(4 + g*5 + k)*NPIX + p);
    #pragma unroll
    for (int k = 0; k < 5; ++k) {
      int c = g*5 + k;
      float sg0 = fast_sigmoid(svb[k].x);
      float sg1 = fast_sigmoid(svb[k].y);
      Sv0 += sg0*sg0;
      Sv1 += sg1*sg1;
      if (c + 1 == lbv.x) so0 = sg0;
      if (c + 1 == lbv.y) so1 = sg1;
    }
  }
  float seedloc = 0.f, vloc = 0.f;
  if (lbv.x != 255) { seedloc += Sv0 - so0*so0; vloc += 1.0f; }
  if (lbv.y != 255) { seedloc += Sv1 - so1*so1; vloc += 1.0f; }

  // rec: {f16 ex, f16 ey, u8 sg_own, u8 (id | valid<<7)}
  {
    uint2 r4[2];
    #pragma unroll
    for (int u = 0; u < 2; ++u) {
      int px = p + u;
      int x = px & (WW-1);
      int y = px >> 9;
      float ex = fast_tanh((&e0v.x)[u]) + x * (1.0f/(WW-1));
      float ey = fast_tanh((&e1v.x)[u]) + y * (1.0f/(HH-1));
      __half2 h = __floats2half2_rn(ex, ey);
      unsigned valid = (((&lbv.x)[u]) != 255) ? 1u : 0u;
      unsigned meta = (unsigned)(&idv.x)[u] | (valid << 7);
      float sou = u ? so1 : so0;
      r4[u].x = *reinterpret_cast<unsigned*>(&h);
      r4[u].y = (unsigned)(unsigned char)(sou*255.f + 0.5f) | (meta << 8);
    }
    *(uint4*)(rec + (size_t)b*NPIX + p) = make_uint4(r4[0].x, r4[0].y, r4[1].x, r4[1].y);
  }
  for (int o = 32; o; o >>= 1) {
    seedloc += __shfl_down(seedloc, o);
    vloc    += __shfl_down(vloc, o);
  }
  if ((t & 63) == 0) { atomicAdd(&s_seed, seedloc); atomicAdd(&s_valid, vloc); }
  __syncthreads();

  {
    int j = t & 31, f = t >> 5;
    float v;
    if (f == 0) {
      unsigned s = (s_st[0][j][0] & 0xFFFFu) + (s_st[1][j][0] & 0xFFFFu)
                 + (s_st[2][j][0] & 0xFFFFu) + (s_st[3][j][0] & 0xFFFFu);
      v = (float)s;
    } else if (f == 7) {
      unsigned s = (s_st[0][j][0] >> 16) + (s_st[1][j][0] >> 16)
                 + (s_st[2][j][0] >> 16) + (s_st[3][j][0] >> 16);
      v = (float)s;
    } else {
      v = __uint_as_float(s_st[0][j][f]) + __uint_as_float(s_st[1][j][f])
        + __uint_as_float(s_st[2][j][f]) + __uint_as_float(s_st[3][j][f]);
    }
    partA[(blockIdx.x << 8) + t] = v;
  }
  if (t == 0) partSeed[blockIdx.x] = make_float2(s_seed, s_valid);
}

// K2a: 33 blocks (unchanged).
__global__ __launch_bounds__(256) void k2a_reduce(
    const float* __restrict__ partA, const float2* __restrict__ partSeed,
    float* __restrict__ stats, float* __restrict__ seedbg,
    float* __restrict__ validT)
{
  int bid = blockIdx.x;
  int t = threadIdx.x;
  if (bid < 32) {
    __shared__ float red[256];
    int b = bid >> 3, f = bid & 7;
    int j = t & 31, grp = t >> 5;           // 8 groups x 64 blocks
    float s = 0.f;
    #pragma unroll 8
    for (int k = 0; k < 64; ++k)
      s += partA[((b*512 + grp*64 + k) << 8) + (f << 5) + j];
    red[t] = s; __syncthreads();
    for (int st = 128; st >= 32; st >>= 1) {
      if (t < st) red[t] += red[t + st];
      __syncthreads();
    }
    if (t < 32) stats[f*128 + b*32 + t] = red[t];
  } else {
    int img = t >> 6, slot = t & 63;
    float s = 0.f, v = 0.f;
    #pragma unroll
    for (int k = 0; k < 8; ++k) {
      float2 ps = partSeed[img*512 + slot*8 + k];
      s += ps.x; v += ps.y;
    }
    for (int o = 32; o; o >>= 1) {
      s += __shfl_down(s, o);
      v += __shfl_down(v, o);
    }
    if (slot == 0) { seedbg[img] = s; validT[img] = v; }
  }
}

// K3: unchanged structure; NBIN=64 (hist 4MB).
__global__ __launch_bounds__(K3T) void k3_hist(
    const uint2* __restrict__ rec, const float* __restrict__ stats,
    unsigned* __restrict__ hist, float* __restrict__ sfg)
{
  __shared__ unsigned hc[NBIN*HSTR];      // 8.4 KB
  __shared__ float sder[NINST][4];
  __shared__ float s_fg[8];
  int t = threadIdx.x;
  int bid = blockIdx.x;                   // 512
  int b = bid >> 7;
  int chunk = bid & 127;
  for (int i = t; i < NBIN*HSTR; i += K3T) hc[i] = 0u;
  if (t < NINST) {
    int pr = b*NINST + t;
    float cnt = fmaxf(stats[0*128+pr], 1.0f);
    float rc = fast_rcp(cnt);
    sder[t][0] = stats[1*128+pr] * rc;
    sder[t][1] = stats[2*128+pr] * rc;
    sder[t][2] = -1.442695041f * __expf(10.f * stats[3*128+pr] * rc);
    sder[t][3] = -1.442695041f * __expf(10.f * stats[4*128+pr] * rc);
  }
  __syncthreads();

  int w = t >> 6, lane = t & 63;
  int j = lane & 31, jp1 = j + 1;
  float cx = sder[j][0], cy = sder[j][1];
  float s0 = sder[j][2], s1 = sder[j][3];
  const uint4* base4 = (const uint4*)(rec + (size_t)b*NPIX + chunk*CPX3)
                       + w*128 + (lane >> 5);
  unsigned* hrow = hc + j;
  float fg = 0.f;

  #pragma unroll 4
  for (int r = 0; r < 64; ++r) {
    uint4 rv = base4[r*2];
    #pragma unroll
    for (int u = 0; u < 2; ++u) {
      unsigned lo = u ? rv.z : rv.x;
      unsigned hi = u ? rv.w : rv.y;
      __half2 h;
      *reinterpret_cast<unsigned*>(&h) = lo;
      float2 e = __half22float2(h);
      float dx = e.x - cx, dy = e.y - cy;
      float dist = exp2f(dx*dx*s0 + dy*dy*s1);
      bool own = ((int)((hi >> 8) & 0x3F) == jp1);
      if (own) { float d = (float)(hi & 0xFFu)*(1.0f/255.f) - dist; fg += d*d; }
      if (hi & 0x8000u) {
        float f = own ? (1.0f - dist) : dist;
        unsigned bin = min((unsigned)(f * (float)NBIN), NBIN-1u);
        if (bin) atomicAdd(&hrow[bin*HSTR], own ? 0x10001u : 1u);
      }
    }
  }
  for (int o = 32; o; o >>= 1) fg += __shfl_down(fg, o);
  if (lane == 0) s_fg[w] = fg;
  __syncthreads();
  if (t == 0) {
    float s = 0.f;
    #pragma unroll
    for (int i = 0; i < 8; ++i) s += s_fg[i];
    sfg[bid] = 10.0f * s;
  }
  // transposed flush -> hist[b][chunk][inst][bin] (2048 u32, 4/thread)
  unsigned* out = hist + (size_t)(b*NCHUNK3 + chunk) * (NINST*NBIN);
  #pragma unroll
  for (int k = 0; k < NINST*NBIN/K3T; ++k) {
    int idx = k*K3T + t;
    out[idx] = hc[(idx & 63)*HSTR + (idx >> 6)];
  }
}

// K4: per pair: reduce 128 chunk hists (8 grp x 16), reconstruct bin-0,
// single-pass 64-bin Lovasz scan, accumulate into out[0].
__global__ __launch_bounds__(512) void k4_final(
    const unsigned* __restrict__ hist, const float* __restrict__ stats,
    const float* __restrict__ validT, const float* __restrict__ seedbg,
    const float* __restrict__ sfg, float* __restrict__ out)
{
  __shared__ unsigned s_c[8][NBIN], s_p[8][NBIN];
  __shared__ unsigned rc[NBIN], rp[NBIN];
  __shared__ float s_L;
  int t = threadIdx.x;
  int pair = blockIdx.x;
  int b = pair >> 5, j = pair & 31;
  int grp = t >> 6, bin = t & 63;
  const unsigned* bp = hist + ((size_t)b*NCHUNK3*NINST + j)*NBIN + bin;
  unsigned c = 0, p = 0;
  #pragma unroll 8
  for (int ch = grp*16; ch < grp*16 + 16; ++ch) {
    unsigned v = bp[(size_t)ch * (NINST*NBIN)];
    c += v & 0xFFFFu; p += v >> 16;
  }
  s_c[grp][bin] = c; s_p[grp][bin] = p;
  __syncthreads();
  if (t < NBIN) {
    unsigned cc = 0, pp = 0;
    #pragma unroll
    for (int g = 0; g < 8; ++g) { cc += s_c[g][t]; pp += s_p[g][t]; }
    s_c[0][t] = cc; s_p[0][t] = pp;
    rc[t] = t ? cc : 0u; rp[t] = t ? pp : 0u;
  }
  __syncthreads();
  for (int st = 32; st; st >>= 1) {
    if (t < st) { rc[t] += rc[t+st]; rp[t] += rp[t+st]; }
    __syncthreads();
  }
  float G = stats[7*128+pair];
  if (t == 0) {
    s_c[0][0] = (unsigned)validT[b] - rc[0];
    s_p[0][0] = (unsigned)G - rp[0];
  }
  __syncthreads();

  if (t < 64) {
    int lane = t;
    int k = NBIN - 1 - lane;              // descending
    unsigned n = s_c[0][k], pp0 = s_p[0][k];
    for (int off = 1; off < 64; off <<= 1) {
      unsigned nn = __shfl_up(n, off);
      unsigned pq = __shfl_up(pp0, off);
      if (lane >= off) { n += nn; pp0 += pq; }
    }
    float fN = (float)n;
    float fP = (float)pp0;
    float uni = G + fN - fP;
    float J = 1.0f - (G - fP) / fmaxf(uni, 1e-9f);
    float Jp = __shfl_up(J, 1);
    if (lane == 0) Jp = 0.f;
    float v = (k + 0.5f) * (2.0f/NBIN);
    float L = v * (J - Jp);
    for (int o = 32; o; o >>= 1) L += __shfl_down(L, o);
    if (lane == 0) s_L = L;
  }
  __syncthreads();
  if (t == 0) {
    float cntA = stats[0*128+pair];
    float cnt = fmaxf(cntA, 1.0f);
    float s0 = stats[3*128+pair], s1 = stats[4*128+pair];
    float q0 = stats[5*128+pair], q1 = stats[6*128+pair];
    float sm0 = s0/cnt, sm1 = s1/cnt;
    float varnum = q0 - 2.f*sm0*s0 + cntA*sm0*sm0
                 + q1 - 2.f*sm1*s1 + cntA*sm1*sm1;
    float varl = varnum / (2.0f * cnt);
    atomicAdd(out, (s_L + 10.0f*varl) * (1.0f/(NINST*BB)));
  }
  if (pair == 0) {
    __shared__ float red[512];
    float acc = sfg[t];
    if (t < 4) acc += seedbg[t];
    red[t] = acc; __syncthreads();
    for (int st = 256; st; st >>= 1) {
      if (t < st) red[t] += red[t+st];
      __syncthreads();
    }
    if (t == 0) atomicAdd(out, red[0] * (1.0f/((float)NPIX*BB)));
  }
}

extern "C" void kernel_launch(void* const* d_in, const int* in_sizes, int n_in,
                              void* d_out, int out_size, void* d_ws, size_t ws_size,
                              hipStream_t stream)
{
  const float* pred = (const float*)d_in[0];
  const int* inst = (const int*)d_in[1];
  const int* lab  = (const int*)d_in[2];
  char* ws = (char*)d_ws;
  float* partA = (float*)(ws + OFF_PARTA);
  float2* partSeed = (float2*)(ws + OFF_PSEED);
  float* stats = (float*)(ws + OFF_STATS);
  float* seedbg = (float*)(ws + OFF_SEEDBG);
  float* validT = (float*)(ws + OFF_VALID);
  float* sfg = (float*)(ws + OFF_SFG);
  uint2* rec = (uint2*)(ws + OFF_REC);
  unsigned* hist = (unsigned*)(ws + OFF_HIST);

  hipLaunchKernelGGL(k1_stats, dim3(2048), dim3(256), 0, stream,
                     pred, inst, lab, partA, partSeed, rec, (float*)d_out);
  hipLaunchKernelGGL(k2a_reduce, dim3(33), dim3(256), 0, stream,
                     partA, partSeed, stats, seedbg, validT);
  hipLaunchKernelGGL(k3_hist, dim3(BB*NCHUNK3), dim3(K3T), 0, stream,
                     rec, stats, hist, sfg);
  hipLaunchKernelGGL(k4_final, dim3(128), dim3(512), 0, stream,
                     hist, stats, validT, seedbg, sfg, (float*)d_out);
}